// Round 11
// baseline (30.744 us; speedup 1.0000x reference)
//
#include <hip/hip_runtime.h>

#define NPART 128
#define NDIM  128
#define BATCH 4096
#define BPP   4                       // blocks per particle
#define NBLK  (NPART * BPP)           // 512 blocks
#define NXCD  8

// ---------------------------------------------------------------------------
// Single fused kernel: 512 blocks x 256 threads.
// Block = (particle p, quarter q). Each block independently:
//   1. issues sigma_p stage loads into registers (latency hidden under 2-4),
//   2. computes softmax scalars (m, S) from logp (wave 0),
//   3. ranks samples with randind==p via deterministic 256-wide LDS scan
//      (rank = sid order; all 4 sibling blocks agree -> exact partition),
//   4. writes sigma_p to XOR-swizzled LDS, pulls row i into 32 float4 regs,
//   5. per sample in its quarter: uniform y loads + register fmacs -> out,
//      plus wout/indout (lane i==0).
// No workspace, no atomics, fully deterministic.
// ---------------------------------------------------------------------------
__global__ __launch_bounds__(256)
void mix_kernel(const float* __restrict__ gaussian,  // [BATCH, NDIM]
                const float* __restrict__ logp,      // [NPART]
                const float* __restrict__ pos,       // [NPART, NDIM]
                const float* __restrict__ sigma,     // [NPART, NDIM, NDIM]
                const int*   __restrict__ randind,   // [BATCH]
                float* __restrict__ out,             // [BATCH, NDIM]
                float* __restrict__ wout,            // [BATCH]
                float* __restrict__ indout) {        // [BATCH]
    const int g  = blockIdx.x;
    // XCD-chunked bijective swizzle (512 % 8 == 0): a particle's 4 sibling
    // blocks land on the same XCD -> sigma_p HBM-fetched once, L2-served 3x.
    const int sg = (g % NXCD) * (NBLK / NXCD) + g / NXCD;
    const int p  = sg >> 2;            // particle
    const int q  = sg & 3;             // quarter of bucket
    const int t  = threadIdx.x;
    const int i  = t & 127;            // output row
    const int hf = t >> 7;             // sample-parity half

    __shared__ float4 smat[NDIM * 32];           // 64 KB swizzled sigma_p
    __shared__ int    scn[256];
    __shared__ int    slist[128];                // sids of my quarter
    __shared__ float  smx[2];                    // softmax m, S

    // ---- 1. issue sigma stage loads early (reg-staged: dest is swizzled) ----
    const float4* src = reinterpret_cast<const float4*>(
        sigma + (size_t)p * NDIM * NDIM);
    float4 stg[16];
    #pragma unroll
    for (int w = 0; w < 16; ++w) stg[w] = src[w * 256 + t];

    // ---- 2. softmax scalars by wave 0 ----
    if (t < 64) {
        float a = logp[t], b = logp[t + 64];
        float m = fmaxf(a, b);
        #pragma unroll
        for (int o = 32; o > 0; o >>= 1) m = fmaxf(m, __shfl_xor(m, o));
        float ea = expf(a - m), eb = expf(b - m);
        float s = ea + eb;
        #pragma unroll
        for (int o = 32; o > 0; o >>= 1) s += __shfl_xor(s, o);
        if (t == 0) { smx[0] = m; smx[1] = s; }
    }

    // ---- 3. deterministic selection: thread t owns samples [16t, 16t+16) ----
    const int4* rnd4 = reinterpret_cast<const int4*>(randind);
    int mk[16];
    {
        int4 a = rnd4[t * 4 + 0], b = rnd4[t * 4 + 1],
             c = rnd4[t * 4 + 2], d = rnd4[t * 4 + 3];
        mk[0]=a.x;  mk[1]=a.y;  mk[2]=a.z;  mk[3]=a.w;
        mk[4]=b.x;  mk[5]=b.y;  mk[6]=b.z;  mk[7]=b.w;
        mk[8]=c.x;  mk[9]=c.y;  mk[10]=c.z; mk[11]=c.w;
        mk[12]=d.x; mk[13]=d.y; mk[14]=d.z; mk[15]=d.w;
    }
    int cnt = 0;
    #pragma unroll
    for (int k = 0; k < 16; ++k) cnt += (mk[k] == p) ? 1 : 0;
    scn[t] = cnt;
    __syncthreads();
    #pragma unroll
    for (int d = 1; d < 256; d <<= 1) {   // Hillis-Steele inclusive scan
        int v = (t >= d) ? scn[t - d] : 0;
        __syncthreads();
        scn[t] += v;
        __syncthreads();
    }
    const int base = scn[t] - cnt;        // exclusive prefix
    const int n    = scn[255];            // bucket size
    const int lo   = (n * q) / BPP;
    const int hi   = (n * (q + 1)) / BPP;
    {
        int r = base;
        #pragma unroll
        for (int k = 0; k < 16; ++k) {
            if (mk[k] == p) {
                if (r >= lo && r < hi) slist[r - lo] = t * 16 + k;
                ++r;
            }
        }
    }

    // ---- 4. sigma -> LDS (XOR-swizzled 16B units), row -> registers ----
    #pragma unroll
    for (int w = 0; w < 16; ++w) {
        int idx = w * 256 + t;                   // linear float4 index
        int r = idx >> 5, u = idx & 31;
        smat[r * 32 + (u ^ (r & 7))] = stg[w];
    }
    __syncthreads();

    float4 sr[32];
    #pragma unroll
    for (int u = 0; u < 32; ++u)
        sr[u] = smat[i * 32 + (u ^ (i & 7))];

    const float posv = pos[p * NDIM + i];
    const float pw   = expf(logp[p] - smx[0]) / smx[1];

    // ---- 5. per-sample: uniform y row + register fmacs ----
    const int nq = hi - lo;
    for (int s = hf; s < nq; s += 2) {
        const int sid = __builtin_amdgcn_readfirstlane(slist[s]);
        const float4* y = reinterpret_cast<const float4*>(
            gaussian + (size_t)sid * NDIM);
        float a0 = 0.f, a1 = 0.f, a2 = 0.f, a3 = 0.f;
        #pragma unroll
        for (int u = 0; u < 32; ++u) {
            float4 yv = y[u];                    // wave-uniform -> scalar path
            float4 sv = sr[u];
            a0 += sv.x * yv.x;  a1 += sv.y * yv.y;
            a2 += sv.z * yv.z;  a3 += sv.w * yv.w;
        }
        out[sid * NDIM + i] = posv + ((a0 + a1) + (a2 + a3));
        if (i == 0) {
            wout[sid]   = pw;
            indout[sid] = (float)p;              // exact for 0..127
        }
    }
}

extern "C" void kernel_launch(void* const* d_in, const int* in_sizes, int n_in,
                              void* d_out, int out_size, void* d_ws, size_t ws_size,
                              hipStream_t stream) {
    const float* gaussian = (const float*)d_in[0];   // [4096,128]
    const float* logp     = (const float*)d_in[1];   // [128,1]
    const float* pos      = (const float*)d_in[2];   // [128,128]
    const float* sigma    = (const float*)d_in[3];   // [128,128,128]
    const int*   randind  = (const int*)d_in[4];     // [4096]

    float* out    = (float*)d_out;            // [4096*128]
    float* wout   = out + BATCH * NDIM;       // [4096]
    float* indout = wout + BATCH;             // [4096]

    mix_kernel<<<NBLK, 256, 0, stream>>>(gaussian, logp, pos, sigma, randind,
                                         out, wout, indout);
}

// Round 12
// 16.030 us; speedup vs baseline: 1.9179x; 1.9179x over previous
//
#include <hip/hip_runtime.h>

#define NPART 128
#define NDIM  128
#define BATCH 4096
#define BPP   4                       // blocks per particle
#define NBLK  (NPART * BPP)           // 512 blocks
#define NXCD  8

// ---------------------------------------------------------------------------
// Single fused kernel: 512 blocks x 256 threads. Block = (particle p, qtr q).
// Order of operations is register-pressure-disciplined (R11 post-mortem):
//   1. randind loads FIRST (selection not blocked by sigma vmcnt),
//   2. softmax scalars (wave 0) -> LDS,
//   3. selection via wave-shfl scan (no barriers) + 1 barrier for wave totals,
//      rank = sid order -> deterministic exact partition across siblings,
//   4. sigma staged load->ds_write per iteration (transient regs only),
//   5. barrier; row i -> 32 float4 regs; per-sample uniform y + fmacs.
// No workspace, no atomics, fully deterministic.
// ---------------------------------------------------------------------------
__global__ __launch_bounds__(256)
void mix_kernel(const float* __restrict__ gaussian,  // [BATCH, NDIM]
                const float* __restrict__ logp,      // [NPART]
                const float* __restrict__ pos,       // [NPART, NDIM]
                const float* __restrict__ sigma,     // [NPART, NDIM, NDIM]
                const int*   __restrict__ randind,   // [BATCH]
                float* __restrict__ out,             // [BATCH, NDIM]
                float* __restrict__ wout,            // [BATCH]
                float* __restrict__ indout) {        // [BATCH]
    const int g  = blockIdx.x;
    // XCD-chunked bijective swizzle (512 % 8 == 0): a particle's 4 sibling
    // blocks land on the same XCD -> sigma_p HBM-fetched once, L2-served 3x.
    const int sg = (g % NXCD) * (NBLK / NXCD) + g / NXCD;
    const int p  = sg >> 2;            // particle
    const int q  = sg & 3;             // quarter of bucket
    const int t  = threadIdx.x;
    const int i  = t & 127;            // output row
    const int hf = t >> 7;             // sample-parity half
    const int lane = t & 63, wid = t >> 6;

    __shared__ float4 smat[NDIM * 32];           // 64 KB swizzled sigma_p
    __shared__ int    wtot[4];
    __shared__ int    slist[160];                // sids of my quarter
    __shared__ float  smx[2];                    // softmax m, S

    // ---- 1. selection loads first: thread t owns samples [16t, 16t+16) ----
    const int4* rnd4 = reinterpret_cast<const int4*>(randind);
    int mk[16];
    {
        int4 a = rnd4[t * 4 + 0], b = rnd4[t * 4 + 1],
             c = rnd4[t * 4 + 2], d = rnd4[t * 4 + 3];
        mk[0]=a.x;  mk[1]=a.y;  mk[2]=a.z;  mk[3]=a.w;
        mk[4]=b.x;  mk[5]=b.y;  mk[6]=b.z;  mk[7]=b.w;
        mk[8]=c.x;  mk[9]=c.y;  mk[10]=c.z; mk[11]=c.w;
        mk[12]=d.x; mk[13]=d.y; mk[14]=d.z; mk[15]=d.w;
    }

    // ---- 2. softmax scalars by wave 0 ----
    if (t < 64) {
        float a = logp[t], b = logp[t + 64];
        float m = fmaxf(a, b);
        #pragma unroll
        for (int o = 32; o > 0; o >>= 1) m = fmaxf(m, __shfl_xor(m, o));
        float ea = expf(a - m), eb = expf(b - m);
        float s = ea + eb;
        #pragma unroll
        for (int o = 32; o > 0; o >>= 1) s += __shfl_xor(s, o);
        if (t == 0) { smx[0] = m; smx[1] = s; }
    }

    // ---- 3. wave-shfl scan selection (2 barriers total in kernel) ----
    int cnt = 0;
    #pragma unroll
    for (int k = 0; k < 16; ++k) cnt += (mk[k] == p) ? 1 : 0;
    int v = cnt;                                   // inclusive wave scan
    #pragma unroll
    for (int o = 1; o < 64; o <<= 1) {
        int u = __shfl_up(v, o);
        if (lane >= o) v += u;
    }
    if (lane == 63) wtot[wid] = v;
    __syncthreads();                               // barrier #1
    int woff = 0;
    #pragma unroll
    for (int w = 0; w < 4; ++w) woff += (w < wid) ? wtot[w] : 0;
    const int base = woff + v - cnt;               // block-wide exclusive
    const int n    = wtot[0] + wtot[1] + wtot[2] + wtot[3];
    const int lo   = (n * q) / BPP;
    const int hi   = (n * (q + 1)) / BPP;
    const int nq   = hi - lo;
    {
        int r = base;
        #pragma unroll
        for (int k = 0; k < 16; ++k) {
            if (mk[k] == p) {
                if (r >= lo && r < hi) slist[r - lo] = t * 16 + k;
                ++r;
            }
        }
    }
    if (nq == 0) return;               // uniform across block, safe

    // ---- 4. sigma -> LDS (XOR-swizzled 16B units), transient regs ----
    const float4* src = reinterpret_cast<const float4*>(
        sigma + (size_t)p * NDIM * NDIM);
    #pragma unroll
    for (int w = 0; w < 16; ++w) {
        int idx = w * 256 + t;                   // linear float4 index
        int r = idx >> 5, u = idx & 31;
        smat[r * 32 + (u ^ (r & 7))] = src[idx];
    }
    __syncthreads();                               // barrier #2

    // ---- 5. row i -> 32 float4 regs; per-sample uniform y + fmacs ----
    float4 sr[32];
    #pragma unroll
    for (int u = 0; u < 32; ++u)
        sr[u] = smat[i * 32 + (u ^ (i & 7))];

    const float posv = pos[p * NDIM + i];
    const float pw   = expf(logp[p] - smx[0]) / smx[1];

    for (int s = hf; s < nq; s += 2) {
        const int sid = __builtin_amdgcn_readfirstlane(slist[s]);
        const float4* y = reinterpret_cast<const float4*>(
            gaussian + (size_t)sid * NDIM);
        float a0 = 0.f, a1 = 0.f, a2 = 0.f, a3 = 0.f;
        #pragma unroll
        for (int u = 0; u < 32; ++u) {
            float4 yv = y[u];                    // wave-uniform -> scalar path
            float4 sv = sr[u];
            a0 += sv.x * yv.x;  a1 += sv.y * yv.y;
            a2 += sv.z * yv.z;  a3 += sv.w * yv.w;
        }
        out[sid * NDIM + i] = posv + ((a0 + a1) + (a2 + a3));
        if (i == 0) {
            wout[sid]   = pw;
            indout[sid] = (float)p;              // exact for 0..127
        }
    }
}

extern "C" void kernel_launch(void* const* d_in, const int* in_sizes, int n_in,
                              void* d_out, int out_size, void* d_ws, size_t ws_size,
                              hipStream_t stream) {
    const float* gaussian = (const float*)d_in[0];   // [4096,128]
    const float* logp     = (const float*)d_in[1];   // [128,1]
    const float* pos      = (const float*)d_in[2];   // [128,128]
    const float* sigma    = (const float*)d_in[3];   // [128,128,128]
    const int*   randind  = (const int*)d_in[4];     // [4096]

    float* out    = (float*)d_out;            // [4096*128]
    float* wout   = out + BATCH * NDIM;       // [4096]
    float* indout = wout + BATCH;             // [4096]

    mix_kernel<<<NBLK, 256, 0, stream>>>(gaussian, logp, pos, sigma, randind,
                                         out, wout, indout);
}